// Round 8
// baseline (250.398 us; speedup 1.0000x reference)
//
#include <hip/hip_runtime.h>
#include <hip/hip_bf16.h>

#define SEP_ID 2
#define S_LEN  4096
#define HID    768
#define MAXS   64

using short8  = __attribute__((ext_vector_type(8))) short;  // 8 bf16 (4 VGPRs)
using floatx4 = __attribute__((ext_vector_type(4))) float;  // MFMA accumulator

__device__ __forceinline__ float gelu_exact(float x) {
    return 0.5f * x * (1.0f + erff(x * 0.70710678118654752f));
}

__device__ __forceinline__ unsigned pack_bf16x2(float lo, float hi) {
    __hip_bfloat16 a = __float2bfloat16(lo);
    __hip_bfloat16 b = __float2bfloat16(hi);
    return ((unsigned)*(unsigned short*)&b << 16) | (unsigned)*(unsigned short*)&a;
}

// ---------------------------------------------------------------------------
// K1 "stage1": pool blocks [0,512) + weight-transpose blocks [512,4608).
// Pool blocks self-compute bounds from ids (shfl prefix-scan), then mean-pool
// with float4 columns and an 8-row unroll. Block 0 also zeroes cnt[].
// (R7 lesson: keep the one-time fp32->bf16 transpose — it amortizes weight
// reads across all GEMM blocks; per-block fp32 staging cost +48 us.)
// ---------------------------------------------------------------------------
__global__ __launch_bounds__(256) void stage1_kernel(const int* __restrict__ ids,
                                                     const float* __restrict__ hidden,
                                                     const float* __restrict__ W1,
                                                     const float* __restrict__ W2,
                                                     __hip_bfloat16* __restrict__ W1T,
                                                     __hip_bfloat16* __restrict__ W2T,
                                                     __hip_bfloat16* __restrict__ sentb,
                                                     int* __restrict__ cnt) {
    __shared__ __align__(16) char smem[16640];
    const int blk = blockIdx.x;
    const int t = threadIdx.x;

    if (blk < 512) {
        if (blk == 0 && t >= 248) cnt[t - 248] = 0;   // zero 8 completion ctrs

        // ---- self-bounds ----
        int* sep_pos = (int*)smem;            // 4096 ints
        int* wtot    = sep_pos + 4096;        // 4 ints
        const int sidx = blk;
        const int b = sidx >> 6, m = sidx & 63;
        const int* row = ids + (size_t)b * S_LEN;
        const int lane = t & 63, w = t >> 6;

        int local[16]; int c = 0;
        const int base = t * 16;
        #pragma unroll
        for (int q = 0; q < 4; ++q) {
            int4 v = ((const int4*)row)[t * 4 + q];
            if (v.x == SEP_ID) local[c++] = base + q * 4 + 0;
            if (v.y == SEP_ID) local[c++] = base + q * 4 + 1;
            if (v.z == SEP_ID) local[c++] = base + q * 4 + 2;
            if (v.w == SEP_ID) local[c++] = base + q * 4 + 3;
        }
        int scan = c;                              // inclusive wave prefix
        #pragma unroll
        for (int off = 1; off < 64; off <<= 1) {
            int n = __shfl_up(scan, off);
            if (lane >= off) scan += n;
        }
        if (lane == 63) wtot[w] = scan;
        __syncthreads();
        int wbase = 0;
        for (int i = 0; i < w; ++i) wbase += wtot[i];
        const int o = wbase + scan - c;
        for (int i = 0; i < c; ++i) sep_pos[o + i] = local[i];
        __syncthreads();
        const int n_sep = wtot[0] + wtot[1] + wtot[2] + wtot[3];

        // ---- reference segment semantics ----
        int start = 0, cntok = 0;
        if (n_sep == 0) {
            if (m == 0) { start = 0; cntok = S_LEN; }
        } else if (m < n_sep) {
            if (m == 0) { start = 0; cntok = sep_pos[0] + 1; }   // includes first sep
            else { start = sep_pos[m - 1] + 1; cntok = sep_pos[m] - sep_pos[m - 1] - 1; }
        } else if (m == n_sep) {
            start = sep_pos[n_sep - 1] + 1;                      // trailing segment
            cntok = (S_LEN - 1) - start;                         // excludes token S-1
            if (cntok < 0) cntok = 0;
        }

        // ---- mean pool ----
        if (t < 192) {
            const float4* bp = (const float4*)(hidden + ((size_t)b * S_LEN + start) * HID);
            float ax = 0.f, ay = 0.f, az = 0.f, aw = 0.f;
            int i = 0;
            for (; i + 8 <= cntok; i += 8) {
                float4 v[8];
                #pragma unroll
                for (int j = 0; j < 8; ++j) v[j] = bp[(size_t)(i + j) * 192 + t];
                #pragma unroll
                for (int j = 0; j < 8; ++j) { ax += v[j].x; ay += v[j].y; az += v[j].z; aw += v[j].w; }
            }
            for (; i < cntok; ++i) {
                float4 v = bp[(size_t)i * 192 + t];
                ax += v.x; ay += v.y; az += v.z; aw += v.w;
            }
            const float inv = (cntok > 0) ? 1.0f / (float)cntok : 0.0f;
            uint2 pk = { pack_bf16x2(ax * inv, ay * inv),
                         pack_bf16x2(az * inv, aw * inv) };
            *(uint2*)(sentb + (size_t)sidx * HID + t * 4) = pk;   // one 8B store
        }
    } else {
        // ---- weight transpose fp32[K][N] -> bf16[N][K], one 32x32 tile ----
        float* tile = (float*)smem;           // [32][33]
        const int id0 = blk - 512;
        const float* in; __hip_bfloat16* outw; int K, N, n0, k0;
        if (id0 < 3072) { in = W1; outw = W1T; K = 768;  N = 4096;
                          n0 = (id0 & 127) * 32; k0 = (id0 >> 7) * 32; }
        else { const int id = id0 - 3072;
               in = W2; outw = W2T; K = 4096; N = 256;
               n0 = (id & 7) * 32; k0 = (id >> 3) * 32; }
        const int c = t & 31;
        const int r = t >> 5;
        #pragma unroll
        for (int i = 0; i < 32; i += 8)
            tile[(r + i) * 33 + c] = in[(size_t)(k0 + r + i) * N + n0 + c];
        __syncthreads();
        #pragma unroll
        for (int i = 0; i < 32; i += 8)
            outw[(size_t)(n0 + r + i) * K + k0 + c] = __float2bfloat16(tile[c * 33 + r + i]);
    }
}

// ---------------------------------------------------------------------------
// K2: GEMM1  x1 = GELU(sentb[512,768] @ W1T[4096,768]^T + b1), bf16 out.
// 64x64 tile, BK=128 (6 K-iters), grid (64,8)=512 blocks (2/CU).
// 4 waves 2x2; each wave 32x32 via 2x2 MFMA x 4 k-steps = 16 MFMA/iter.
// Epilogue bounces through LDS for coalesced 32B stores. (R6-identical.)
// ---------------------------------------------------------------------------
__global__ __launch_bounds__(256) void gemm1_kernel(const __hip_bfloat16* __restrict__ A,
                                                    const __hip_bfloat16* __restrict__ BT,
                                                    const float* __restrict__ bias,
                                                    __hip_bfloat16* __restrict__ out) {
    const int n0 = blockIdx.x * 64;
    const int m0 = blockIdx.y * 64;
    const int t = threadIdx.x;
    const int w = t >> 6, l = t & 63;
    const int wm = (w >> 1) * 32;
    const int wn = (w & 1) * 32;

    __shared__ __hip_bfloat16 Al[64][136];
    __shared__ __hip_bfloat16 Bl[64][136];

    floatx4 acc[2][2] = {};

    const int r  = t >> 2;            // 0..63
    const int ch = (t & 3) * 32;      // 64B contiguous per thread
    const __hip_bfloat16* Ag = A  + (size_t)(m0 + r) * 768 + ch;
    const __hip_bfloat16* Bg = BT + (size_t)(n0 + r) * 768 + ch;

    const int lr = l & 15;
    const int kq = (l >> 4) * 8;

    for (int k0 = 0; k0 < 768; k0 += 128) {
        short8 av[4], bv[4];
        #pragma unroll
        for (int q = 0; q < 4; ++q) {
            av[q] = *(const short8*)(Ag + k0 + q * 8);
            bv[q] = *(const short8*)(Bg + k0 + q * 8);
        }
        __syncthreads();
        #pragma unroll
        for (int q = 0; q < 4; ++q) {
            *(short8*)(&Al[r][ch + q * 8]) = av[q];
            *(short8*)(&Bl[r][ch + q * 8]) = bv[q];
        }
        __syncthreads();

        #pragma unroll
        for (int ks = 0; ks < 128; ks += 32) {
            short8 a0 = *(const short8*)(&Al[wm + lr][ks + kq]);
            short8 a1 = *(const short8*)(&Al[wm + 16 + lr][ks + kq]);
            short8 b0 = *(const short8*)(&Bl[wn + lr][ks + kq]);
            short8 b1 = *(const short8*)(&Bl[wn + 16 + lr][ks + kq]);
            acc[0][0] = __builtin_amdgcn_mfma_f32_16x16x32_bf16(a0, b0, acc[0][0], 0, 0, 0);
            acc[0][1] = __builtin_amdgcn_mfma_f32_16x16x32_bf16(a0, b1, acc[0][1], 0, 0, 0);
            acc[1][0] = __builtin_amdgcn_mfma_f32_16x16x32_bf16(a1, b0, acc[1][0], 0, 0, 0);
            acc[1][1] = __builtin_amdgcn_mfma_f32_16x16x32_bf16(a1, b1, acc[1][1], 0, 0, 0);
        }
    }

    // ---- epilogue: bias + GELU -> LDS [64][72] -> coalesced 32B stores ----
    __syncthreads();
    __hip_bfloat16* E = &Al[0][0];              // reuse, stride 72
    #pragma unroll
    for (int i = 0; i < 2; ++i) {
        #pragma unroll
        for (int j = 0; j < 2; ++j) {
            const int cl = wn + j * 16 + lr;
            const float bv = bias[n0 + cl];
            #pragma unroll
            for (int rg = 0; rg < 4; ++rg) {
                const int rl = wm + i * 16 + (l >> 4) * 4 + rg;
                float x = acc[i][j][rg] + bv;
                E[rl * 72 + cl] = __float2bfloat16(gelu_exact(x));
            }
        }
    }
    __syncthreads();
    {
        const int rr  = t >> 2;
        const int seg = (t & 3) * 16;
        short8 v0 = *(const short8*)(&E[rr * 72 + seg]);
        short8 v1 = *(const short8*)(&E[rr * 72 + seg + 8]);
        __hip_bfloat16* op = out + (size_t)(m0 + rr) * 4096 + n0 + seg;
        *(short8*)(op)     = v0;
        *(short8*)(op + 8) = v1;
    }
}

// ---------------------------------------------------------------------------
// K3: GEMM2 split-K=8 partials (plain stores, R6 path) + fused reduce+head.
// Grid (4,8,8) = 256 blocks. After storing its 64x64 fp32 partial tile, each
// block fences + bumps cnt[m-tile]; the 32nd (last) block for that m-tile
// reduces the 8 partials and runs b2+GELU+head for its 64 rows.
// ---------------------------------------------------------------------------
__global__ __launch_bounds__(256) void gemm2_kernel(const __hip_bfloat16* __restrict__ A,
                                                    const __hip_bfloat16* __restrict__ BT,
                                                    const float* __restrict__ b2,
                                                    const float* __restrict__ W3,
                                                    const float* __restrict__ b3,
                                                    float* __restrict__ part,
                                                    int* __restrict__ cnt,
                                                    float* __restrict__ out) {
    const int n0 = blockIdx.x * 64;
    const int m0 = blockIdx.y * 64;
    const int s  = blockIdx.z;
    const int kb = s * 512;
    const int t = threadIdx.x;
    const int w = t >> 6, l = t & 63;
    const int wm = (w >> 1) * 32;
    const int wn = (w & 1) * 32;

    __shared__ __hip_bfloat16 Al[64][136];
    __shared__ __hip_bfloat16 Bl[64][136];
    __shared__ int lastflag;

    floatx4 acc[2][2] = {};

    const int r  = t >> 2;
    const int ch = (t & 3) * 32;
    const __hip_bfloat16* Ag = A  + (size_t)(m0 + r) * 4096 + kb + ch;
    const __hip_bfloat16* Bg = BT + (size_t)(n0 + r) * 4096 + kb + ch;

    const int lr = l & 15;
    const int kq = (l >> 4) * 8;

    for (int k0 = 0; k0 < 512; k0 += 128) {
        short8 av[4], bv[4];
        #pragma unroll
        for (int q = 0; q < 4; ++q) {
            av[q] = *(const short8*)(Ag + k0 + q * 8);
            bv[q] = *(const short8*)(Bg + k0 + q * 8);
        }
        __syncthreads();
        #pragma unroll
        for (int q = 0; q < 4; ++q) {
            *(short8*)(&Al[r][ch + q * 8]) = av[q];
            *(short8*)(&Bl[r][ch + q * 8]) = bv[q];
        }
        __syncthreads();

        #pragma unroll
        for (int ks = 0; ks < 128; ks += 32) {
            short8 a0 = *(const short8*)(&Al[wm + lr][ks + kq]);
            short8 a1 = *(const short8*)(&Al[wm + 16 + lr][ks + kq]);
            short8 b0 = *(const short8*)(&Bl[wn + lr][ks + kq]);
            short8 b1 = *(const short8*)(&Bl[wn + 16 + lr][ks + kq]);
            acc[0][0] = __builtin_amdgcn_mfma_f32_16x16x32_bf16(a0, b0, acc[0][0], 0, 0, 0);
            acc[0][1] = __builtin_amdgcn_mfma_f32_16x16x32_bf16(a0, b1, acc[0][1], 0, 0, 0);
            acc[1][0] = __builtin_amdgcn_mfma_f32_16x16x32_bf16(a1, b0, acc[1][0], 0, 0, 0);
            acc[1][1] = __builtin_amdgcn_mfma_f32_16x16x32_bf16(a1, b1, acc[1][1], 0, 0, 0);
        }
    }

    // ---- store fp32 partial tile (plain coalesced stores) ----
    float* po = part + (size_t)s * 512 * 256;
    #pragma unroll
    for (int i = 0; i < 2; ++i) {
        #pragma unroll
        for (int j = 0; j < 2; ++j) {
            const int col  = n0 + wn + j * 16 + lr;
            const int rowb = m0 + wm + i * 16 + (l >> 4) * 4;
            #pragma unroll
            for (int rg = 0; rg < 4; ++rg)
                po[(size_t)(rowb + rg) * 256 + col] = acc[i][j][rg];
        }
    }

    // ---- completion: last of 32 blocks for this m-tile runs reduce+head ----
    __threadfence();                       // release partial stores
    __syncthreads();
    if (t == 0) {
        int old = atomicAdd(&cnt[blockIdx.y], 1);
        lastflag = (old == 31);
    }
    __syncthreads();
    if (!lastflag) return;
    __threadfence();                       // acquire others' partial stores

    // wave w handles row m0 + it*4 + w; lane l covers cols l + 64q.
    for (int it = 0; it < 16; ++it) {
        const int row = m0 + it * 4 + w;
        float y0 = 0.f, y1 = 0.f;
        #pragma unroll
        for (int q = 0; q < 4; ++q) {
            const int col = l + 64 * q;
            float v = 0.f;
            #pragma unroll
            for (int k = 0; k < 8; ++k)
                v += part[((size_t)k * 512 + row) * 256 + col];
            const float x = gelu_exact(v + b2[col]);
            y0 += x * W3[col * 2 + 0];
            y1 += x * W3[col * 2 + 1];
        }
        #pragma unroll
        for (int off = 32; off; off >>= 1) {
            y0 += __shfl_down(y0, off);
            y1 += __shfl_down(y1, off);
        }
        if (l == 0) {
            out[row * 2 + 0] = y0 + b3[0];
            out[row * 2 + 1] = y1 + b3[1];
        }
    }
}

// ---------------------------------------------------------------------------
extern "C" void kernel_launch(void* const* d_in, const int* in_sizes, int n_in,
                              void* d_out, int out_size, void* d_ws, size_t ws_size,
                              hipStream_t stream) {
    const float* hidden = (const float*)d_in[0];
    const int*   ids    = (const int*)d_in[1];
    const float* W1     = (const float*)d_in[2];
    const float* b1     = (const float*)d_in[3];
    const float* W2     = (const float*)d_in[4];
    const float* b2     = (const float*)d_in[5];
    const float* W3     = (const float*)d_in[6];
    const float* b3     = (const float*)d_in[7];
    float* out = (float*)d_out;

    char* ws = (char*)d_ws;
    __hip_bfloat16* sentb  = (__hip_bfloat16*)(ws + 0);           // 512x768 bf16
    __hip_bfloat16* W1T    = (__hip_bfloat16*)(ws + 786432);      // 4096x768 bf16
    __hip_bfloat16* W2T    = (__hip_bfloat16*)(ws + 7077888);     // 256x4096 bf16
    __hip_bfloat16* x1     = (__hip_bfloat16*)(ws + 9175040);     // 512x4096 bf16
    float* part            = (float*)(ws + 13369344);             // 8x512x256 f32
    int*   cnt             = (int*)(ws + 17563648);               // 8 ints
    // total ws use: ~17.6 MB

    stage1_kernel<<<4608, 256, 0, stream>>>(ids, hidden, W1, W2, W1T, W2T, sentb, cnt);
    gemm1_kernel<<<dim3(64, 8), 256, 0, stream>>>(sentb, W1T, b1, x1);
    gemm2_kernel<<<dim3(4, 8, 8), 256, 0, stream>>>(x1, W2T, b2, W3, b3, part, cnt, out);
}

// Round 9
// 198.306 us; speedup vs baseline: 1.2627x; 1.2627x over previous
//
#include <hip/hip_runtime.h>
#include <hip/hip_bf16.h>

#define SEP_ID 2
#define S_LEN  4096
#define HID    768
#define MAXS   64

using short8  = __attribute__((ext_vector_type(8))) short;  // 8 bf16 (4 VGPRs)
using floatx4 = __attribute__((ext_vector_type(4))) float;  // MFMA accumulator

__device__ __forceinline__ float gelu_exact(float x) {
    return 0.5f * x * (1.0f + erff(x * 0.70710678118654752f));
}

__device__ __forceinline__ unsigned pack_bf16x2(float lo, float hi) {
    __hip_bfloat16 a = __float2bfloat16(lo);
    __hip_bfloat16 b = __float2bfloat16(hi);
    return ((unsigned)*(unsigned short*)&b << 16) | (unsigned)*(unsigned short*)&a;
}

// ---------------------------------------------------------------------------
// K1 "stage1": pool blocks [0,512) + weight-transpose blocks [512,1536).
// Pool blocks self-compute bounds from ids (shfl prefix-scan), then mean-pool
// with float4 columns and an 8-row unroll. Tconv blocks do 4 32x32 tiles each.
// (R7/R8 lessons: keep the one-time transpose; no device-scope fences.)
// ---------------------------------------------------------------------------
__global__ __launch_bounds__(256) void stage1_kernel(const int* __restrict__ ids,
                                                     const float* __restrict__ hidden,
                                                     const float* __restrict__ W1,
                                                     const float* __restrict__ W2,
                                                     __hip_bfloat16* __restrict__ W1T,
                                                     __hip_bfloat16* __restrict__ W2T,
                                                     __hip_bfloat16* __restrict__ sentb) {
    __shared__ __align__(16) char smem[16640];
    const int blk = blockIdx.x;
    const int t = threadIdx.x;

    if (blk < 512) {
        // ---- self-bounds ----
        int* sep_pos = (int*)smem;            // 4096 ints
        int* wtot    = sep_pos + 4096;        // 4 ints
        const int sidx = blk;
        const int b = sidx >> 6, m = sidx & 63;
        const int* row = ids + (size_t)b * S_LEN;
        const int lane = t & 63, w = t >> 6;

        int local[16]; int c = 0;
        const int base = t * 16;
        #pragma unroll
        for (int q = 0; q < 4; ++q) {
            int4 v = ((const int4*)row)[t * 4 + q];
            if (v.x == SEP_ID) local[c++] = base + q * 4 + 0;
            if (v.y == SEP_ID) local[c++] = base + q * 4 + 1;
            if (v.z == SEP_ID) local[c++] = base + q * 4 + 2;
            if (v.w == SEP_ID) local[c++] = base + q * 4 + 3;
        }
        int scan = c;                              // inclusive wave prefix
        #pragma unroll
        for (int off = 1; off < 64; off <<= 1) {
            int n = __shfl_up(scan, off);
            if (lane >= off) scan += n;
        }
        if (lane == 63) wtot[w] = scan;
        __syncthreads();
        int wbase = 0;
        for (int i = 0; i < w; ++i) wbase += wtot[i];
        const int o = wbase + scan - c;
        for (int i = 0; i < c; ++i) sep_pos[o + i] = local[i];
        __syncthreads();
        const int n_sep = wtot[0] + wtot[1] + wtot[2] + wtot[3];

        // ---- reference segment semantics ----
        int start = 0, cntok = 0;
        if (n_sep == 0) {
            if (m == 0) { start = 0; cntok = S_LEN; }
        } else if (m < n_sep) {
            if (m == 0) { start = 0; cntok = sep_pos[0] + 1; }   // includes first sep
            else { start = sep_pos[m - 1] + 1; cntok = sep_pos[m] - sep_pos[m - 1] - 1; }
        } else if (m == n_sep) {
            start = sep_pos[n_sep - 1] + 1;                      // trailing segment
            cntok = (S_LEN - 1) - start;                         // excludes token S-1
            if (cntok < 0) cntok = 0;
        }

        // ---- mean pool ----
        if (t < 192) {
            const float4* bp = (const float4*)(hidden + ((size_t)b * S_LEN + start) * HID);
            float ax = 0.f, ay = 0.f, az = 0.f, aw = 0.f;
            int i = 0;
            for (; i + 8 <= cntok; i += 8) {
                float4 v[8];
                #pragma unroll
                for (int j = 0; j < 8; ++j) v[j] = bp[(size_t)(i + j) * 192 + t];
                #pragma unroll
                for (int j = 0; j < 8; ++j) { ax += v[j].x; ay += v[j].y; az += v[j].z; aw += v[j].w; }
            }
            for (; i < cntok; ++i) {
                float4 v = bp[(size_t)i * 192 + t];
                ax += v.x; ay += v.y; az += v.z; aw += v.w;
            }
            const float inv = (cntok > 0) ? 1.0f / (float)cntok : 0.0f;
            uint2 pk = { pack_bf16x2(ax * inv, ay * inv),
                         pack_bf16x2(az * inv, aw * inv) };
            *(uint2*)(sentb + (size_t)sidx * HID + t * 4) = pk;   // one 8B store
        }
    } else {
        // ---- weight transpose fp32[K][N] -> bf16[N][K], 4 tiles per block ----
        float* tile = (float*)smem;           // [32][33]
        const int c = t & 31;
        const int r = t >> 5;
        #pragma unroll
        for (int it = 0; it < 4; ++it) {
            const int id0 = (blk - 512) * 4 + it;
            const float* in; __hip_bfloat16* outw; int K, N, n0, k0;
            if (id0 < 3072) { in = W1; outw = W1T; K = 768;  N = 4096;
                              n0 = (id0 & 127) * 32; k0 = (id0 >> 7) * 32; }
            else { const int id = id0 - 3072;
                   in = W2; outw = W2T; K = 4096; N = 256;
                   n0 = (id & 7) * 32; k0 = (id >> 3) * 32; }
            #pragma unroll
            for (int i = 0; i < 32; i += 8)
                tile[(r + i) * 33 + c] = in[(size_t)(k0 + r + i) * N + n0 + c];
            __syncthreads();
            #pragma unroll
            for (int i = 0; i < 32; i += 8)
                outw[(size_t)(n0 + r + i) * K + k0 + c] = __float2bfloat16(tile[c * 33 + r + i]);
            __syncthreads();
        }
    }
}

// ---------------------------------------------------------------------------
// K2: GEMM1  x1 = GELU(sentb[512,768] @ W1T[4096,768]^T + b1), bf16 out.
// 64x64 tile, BK=128 (6 K-iters), grid (64,8)=512 blocks (2/CU).
// 4 waves 2x2; each wave 32x32 via 2x2 MFMA x 4 k-steps = 16 MFMA/iter.
// Epilogue bounces through LDS for coalesced 32B stores. (R6-identical.)
// ---------------------------------------------------------------------------
__global__ __launch_bounds__(256) void gemm1_kernel(const __hip_bfloat16* __restrict__ A,
                                                    const __hip_bfloat16* __restrict__ BT,
                                                    const float* __restrict__ bias,
                                                    __hip_bfloat16* __restrict__ out) {
    const int n0 = blockIdx.x * 64;
    const int m0 = blockIdx.y * 64;
    const int t = threadIdx.x;
    const int w = t >> 6, l = t & 63;
    const int wm = (w >> 1) * 32;
    const int wn = (w & 1) * 32;

    __shared__ __hip_bfloat16 Al[64][136];
    __shared__ __hip_bfloat16 Bl[64][136];

    floatx4 acc[2][2] = {};

    const int r  = t >> 2;            // 0..63
    const int ch = (t & 3) * 32;      // 64B contiguous per thread
    const __hip_bfloat16* Ag = A  + (size_t)(m0 + r) * 768 + ch;
    const __hip_bfloat16* Bg = BT + (size_t)(n0 + r) * 768 + ch;

    const int lr = l & 15;
    const int kq = (l >> 4) * 8;

    for (int k0 = 0; k0 < 768; k0 += 128) {
        short8 av[4], bv[4];
        #pragma unroll
        for (int q = 0; q < 4; ++q) {
            av[q] = *(const short8*)(Ag + k0 + q * 8);
            bv[q] = *(const short8*)(Bg + k0 + q * 8);
        }
        __syncthreads();
        #pragma unroll
        for (int q = 0; q < 4; ++q) {
            *(short8*)(&Al[r][ch + q * 8]) = av[q];
            *(short8*)(&Bl[r][ch + q * 8]) = bv[q];
        }
        __syncthreads();

        #pragma unroll
        for (int ks = 0; ks < 128; ks += 32) {
            short8 a0 = *(const short8*)(&Al[wm + lr][ks + kq]);
            short8 a1 = *(const short8*)(&Al[wm + 16 + lr][ks + kq]);
            short8 b0 = *(const short8*)(&Bl[wn + lr][ks + kq]);
            short8 b1 = *(const short8*)(&Bl[wn + 16 + lr][ks + kq]);
            acc[0][0] = __builtin_amdgcn_mfma_f32_16x16x32_bf16(a0, b0, acc[0][0], 0, 0, 0);
            acc[0][1] = __builtin_amdgcn_mfma_f32_16x16x32_bf16(a0, b1, acc[0][1], 0, 0, 0);
            acc[1][0] = __builtin_amdgcn_mfma_f32_16x16x32_bf16(a1, b0, acc[1][0], 0, 0, 0);
            acc[1][1] = __builtin_amdgcn_mfma_f32_16x16x32_bf16(a1, b1, acc[1][1], 0, 0, 0);
        }
    }

    // ---- epilogue: bias + GELU -> LDS [64][72] -> coalesced 32B stores ----
    __syncthreads();
    __hip_bfloat16* E = &Al[0][0];              // reuse, stride 72
    #pragma unroll
    for (int i = 0; i < 2; ++i) {
        #pragma unroll
        for (int j = 0; j < 2; ++j) {
            const int cl = wn + j * 16 + lr;
            const float bv = bias[n0 + cl];
            #pragma unroll
            for (int rg = 0; rg < 4; ++rg) {
                const int rl = wm + i * 16 + (l >> 4) * 4 + rg;
                float x = acc[i][j][rg] + bv;
                E[rl * 72 + cl] = __float2bfloat16(gelu_exact(x));
            }
        }
    }
    __syncthreads();
    {
        const int rr  = t >> 2;
        const int seg = (t & 3) * 16;
        short8 v0 = *(const short8*)(&E[rr * 72 + seg]);
        short8 v1 = *(const short8*)(&E[rr * 72 + seg + 8]);
        __hip_bfloat16* op = out + (size_t)(m0 + rr) * 4096 + n0 + seg;
        *(short8*)(op)     = v0;
        *(short8*)(op + 8) = v1;
    }
}

// ---------------------------------------------------------------------------
// K3: GEMM2 partials: part[s] = x1[512, 512-slice] @ W2T[256, 512-slice]^T.
// Split-K=8 (512 K each), BK=128 -> 4 K-iters. Grid (4,8,8)=256 blocks.
// Partial store bounced through LDS (fp32, stride 68) -> 64B/thread float4s.
// ---------------------------------------------------------------------------
__global__ __launch_bounds__(256) void gemm2_kernel(const __hip_bfloat16* __restrict__ A,
                                                    const __hip_bfloat16* __restrict__ BT,
                                                    float* __restrict__ part) {
    const int n0 = blockIdx.x * 64;
    const int m0 = blockIdx.y * 64;
    const int s  = blockIdx.z;
    const int kb = s * 512;
    const int t = threadIdx.x;
    const int w = t >> 6, l = t & 63;
    const int wm = (w >> 1) * 32;
    const int wn = (w & 1) * 32;

    __shared__ __hip_bfloat16 Al[64][136];   // also reused as fp32 [64][68] epilogue
    __shared__ __hip_bfloat16 Bl[64][136];

    floatx4 acc[2][2] = {};

    const int r  = t >> 2;
    const int ch = (t & 3) * 32;
    const __hip_bfloat16* Ag = A  + (size_t)(m0 + r) * 4096 + kb + ch;
    const __hip_bfloat16* Bg = BT + (size_t)(n0 + r) * 4096 + kb + ch;

    const int lr = l & 15;
    const int kq = (l >> 4) * 8;

    for (int k0 = 0; k0 < 512; k0 += 128) {
        short8 av[4], bv[4];
        #pragma unroll
        for (int q = 0; q < 4; ++q) {
            av[q] = *(const short8*)(Ag + k0 + q * 8);
            bv[q] = *(const short8*)(Bg + k0 + q * 8);
        }
        __syncthreads();
        #pragma unroll
        for (int q = 0; q < 4; ++q) {
            *(short8*)(&Al[r][ch + q * 8]) = av[q];
            *(short8*)(&Bl[r][ch + q * 8]) = bv[q];
        }
        __syncthreads();

        #pragma unroll
        for (int ks = 0; ks < 128; ks += 32) {
            short8 a0 = *(const short8*)(&Al[wm + lr][ks + kq]);
            short8 a1 = *(const short8*)(&Al[wm + 16 + lr][ks + kq]);
            short8 b0 = *(const short8*)(&Bl[wn + lr][ks + kq]);
            short8 b1 = *(const short8*)(&Bl[wn + 16 + lr][ks + kq]);
            acc[0][0] = __builtin_amdgcn_mfma_f32_16x16x32_bf16(a0, b0, acc[0][0], 0, 0, 0);
            acc[0][1] = __builtin_amdgcn_mfma_f32_16x16x32_bf16(a0, b1, acc[0][1], 0, 0, 0);
            acc[1][0] = __builtin_amdgcn_mfma_f32_16x16x32_bf16(a1, b0, acc[1][0], 0, 0, 0);
            acc[1][1] = __builtin_amdgcn_mfma_f32_16x16x32_bf16(a1, b1, acc[1][1], 0, 0, 0);
        }
    }

    // ---- epilogue: acc -> LDS fp32 [64][68] -> coalesced 64B/thread stores ----
    __syncthreads();
    float* Ef = (float*)&Al[0][0];           // 64*68*4 = 17408 B == sizeof(Al)
    #pragma unroll
    for (int i = 0; i < 2; ++i) {
        #pragma unroll
        for (int j = 0; j < 2; ++j) {
            const int cl = wn + j * 16 + lr;
            #pragma unroll
            for (int rg = 0; rg < 4; ++rg) {
                const int rl = wm + i * 16 + (l >> 4) * 4 + rg;
                Ef[rl * 68 + cl] = acc[i][j][rg];
            }
        }
    }
    __syncthreads();
    {
        const int rr  = t >> 2;                 // 0..63
        const int seg = (t & 3) * 16;           // 16 floats per thread
        float* po = part + (size_t)s * 512 * 256 + (size_t)(m0 + rr) * 256 + n0 + seg;
        #pragma unroll
        for (int q = 0; q < 4; ++q)
            ((float4*)po)[q] = *(const float4*)(&Ef[rr * 68 + seg + q * 4]);
    }
}

// ---------------------------------------------------------------------------
// K4: fused reduce(8 split-K partials) + b2 + GELU + head (W3[256,2]+b3).
// ---------------------------------------------------------------------------
__global__ __launch_bounds__(256) void rh_kernel(const float* __restrict__ part,
                                                 const float* __restrict__ b2,
                                                 const float* __restrict__ W3,
                                                 const float* __restrict__ b3,
                                                 float* __restrict__ out) {
    const int row = blockIdx.x;     // 512
    const int c = threadIdx.x;      // 256
    const int w = c >> 6, l = c & 63;

    float s = 0.f;
    #pragma unroll
    for (int k = 0; k < 8; ++k)
        s += part[((size_t)k * 512 + row) * 256 + c];
    const float x = gelu_exact(s + b2[c]);
    float y0 = x * W3[c * 2 + 0];
    float y1 = x * W3[c * 2 + 1];
    #pragma unroll
    for (int off = 32; off; off >>= 1) {
        y0 += __shfl_down(y0, off);
        y1 += __shfl_down(y1, off);
    }
    __shared__ float r0[4], r1[4];
    if (l == 0) { r0[w] = y0; r1[w] = y1; }
    __syncthreads();
    if (c == 0) out[row * 2 + 0] = r0[0] + r0[1] + r0[2] + r0[3] + b3[0];
    if (c == 1) out[row * 2 + 1] = r1[0] + r1[1] + r1[2] + r1[3] + b3[1];
}

// ---------------------------------------------------------------------------
extern "C" void kernel_launch(void* const* d_in, const int* in_sizes, int n_in,
                              void* d_out, int out_size, void* d_ws, size_t ws_size,
                              hipStream_t stream) {
    const float* hidden = (const float*)d_in[0];
    const int*   ids    = (const int*)d_in[1];
    const float* W1     = (const float*)d_in[2];
    const float* b1     = (const float*)d_in[3];
    const float* W2     = (const float*)d_in[4];
    const float* b2     = (const float*)d_in[5];
    const float* W3     = (const float*)d_in[6];
    const float* b3     = (const float*)d_in[7];
    float* out = (float*)d_out;

    char* ws = (char*)d_ws;
    __hip_bfloat16* sentb  = (__hip_bfloat16*)(ws + 0);           // 512x768 bf16
    __hip_bfloat16* W1T    = (__hip_bfloat16*)(ws + 786432);      // 4096x768 bf16
    __hip_bfloat16* W2T    = (__hip_bfloat16*)(ws + 7077888);     // 256x4096 bf16
    __hip_bfloat16* x1     = (__hip_bfloat16*)(ws + 9175040);     // 512x4096 bf16
    float* part            = (float*)(ws + 13369344);             // 8x512x256 f32
    // total ws use: ~17.6 MB

    stage1_kernel<<<1536, 256, 0, stream>>>(ids, hidden, W1, W2, W1T, W2T, sentb);
    gemm1_kernel<<<dim3(64, 8), 256, 0, stream>>>(sentb, W1T, b1, x1);
    gemm2_kernel<<<dim3(4, 8, 8), 256, 0, stream>>>(x1, W2T, part);
    rh_kernel<<<512, 256, 0, stream>>>(part, b2, W3, b3, out);
}

// Round 10
// 197.332 us; speedup vs baseline: 1.2689x; 1.0049x over previous
//
#include <hip/hip_runtime.h>
#include <hip/hip_bf16.h>

#define SEP_ID 2
#define S_LEN  4096
#define HID    768
#define MAXS   64

using short8  = __attribute__((ext_vector_type(8))) short;  // 8 bf16 (4 VGPRs)
using floatx4 = __attribute__((ext_vector_type(4))) float;  // MFMA accumulator

__device__ __forceinline__ float gelu_exact(float x) {
    return 0.5f * x * (1.0f + erff(x * 0.70710678118654752f));
}

__device__ __forceinline__ unsigned pack_bf16x2(float lo, float hi) {
    __hip_bfloat16 a = __float2bfloat16(lo);
    __hip_bfloat16 b = __float2bfloat16(hi);
    return ((unsigned)*(unsigned short*)&b << 16) | (unsigned)*(unsigned short*)&a;
}

// ---------------------------------------------------------------------------
// K1 "stage1": pool blocks [0,512) + weight-transpose blocks [512,4608).
// Pool blocks self-compute bounds from ids (shfl prefix-scan), then mean-pool
// with float4 columns and an 8-row unroll. One 32x32 tconv tile per block
// (R9 lesson: 4 tiles/block serializes the transpose tail — keep 1/block).
// (R7/R8 lessons: keep the one-time transpose; no device-scope fences.)
// ---------------------------------------------------------------------------
__global__ __launch_bounds__(256) void stage1_kernel(const int* __restrict__ ids,
                                                     const float* __restrict__ hidden,
                                                     const float* __restrict__ W1,
                                                     const float* __restrict__ W2,
                                                     __hip_bfloat16* __restrict__ W1T,
                                                     __hip_bfloat16* __restrict__ W2T,
                                                     __hip_bfloat16* __restrict__ sentb) {
    __shared__ __align__(16) char smem[16640];
    const int blk = blockIdx.x;
    const int t = threadIdx.x;

    if (blk < 512) {
        // ---- self-bounds ----
        int* sep_pos = (int*)smem;            // 4096 ints
        int* wtot    = sep_pos + 4096;        // 4 ints
        const int sidx = blk;
        const int b = sidx >> 6, m = sidx & 63;
        const int* row = ids + (size_t)b * S_LEN;
        const int lane = t & 63, w = t >> 6;

        int local[16]; int c = 0;
        const int base = t * 16;
        #pragma unroll
        for (int q = 0; q < 4; ++q) {
            int4 v = ((const int4*)row)[t * 4 + q];
            if (v.x == SEP_ID) local[c++] = base + q * 4 + 0;
            if (v.y == SEP_ID) local[c++] = base + q * 4 + 1;
            if (v.z == SEP_ID) local[c++] = base + q * 4 + 2;
            if (v.w == SEP_ID) local[c++] = base + q * 4 + 3;
        }
        int scan = c;                              // inclusive wave prefix
        #pragma unroll
        for (int off = 1; off < 64; off <<= 1) {
            int n = __shfl_up(scan, off);
            if (lane >= off) scan += n;
        }
        if (lane == 63) wtot[w] = scan;
        __syncthreads();
        int wbase = 0;
        for (int i = 0; i < w; ++i) wbase += wtot[i];
        const int o = wbase + scan - c;
        for (int i = 0; i < c; ++i) sep_pos[o + i] = local[i];
        __syncthreads();
        const int n_sep = wtot[0] + wtot[1] + wtot[2] + wtot[3];

        // ---- reference segment semantics ----
        int start = 0, cntok = 0;
        if (n_sep == 0) {
            if (m == 0) { start = 0; cntok = S_LEN; }
        } else if (m < n_sep) {
            if (m == 0) { start = 0; cntok = sep_pos[0] + 1; }   // includes first sep
            else { start = sep_pos[m - 1] + 1; cntok = sep_pos[m] - sep_pos[m - 1] - 1; }
        } else if (m == n_sep) {
            start = sep_pos[n_sep - 1] + 1;                      // trailing segment
            cntok = (S_LEN - 1) - start;                         // excludes token S-1
            if (cntok < 0) cntok = 0;
        }

        // ---- mean pool ----
        if (t < 192) {
            const float4* bp = (const float4*)(hidden + ((size_t)b * S_LEN + start) * HID);
            float ax = 0.f, ay = 0.f, az = 0.f, aw = 0.f;
            int i = 0;
            for (; i + 8 <= cntok; i += 8) {
                float4 v[8];
                #pragma unroll
                for (int j = 0; j < 8; ++j) v[j] = bp[(size_t)(i + j) * 192 + t];
                #pragma unroll
                for (int j = 0; j < 8; ++j) { ax += v[j].x; ay += v[j].y; az += v[j].z; aw += v[j].w; }
            }
            for (; i < cntok; ++i) {
                float4 v = bp[(size_t)i * 192 + t];
                ax += v.x; ay += v.y; az += v.z; aw += v.w;
            }
            const float inv = (cntok > 0) ? 1.0f / (float)cntok : 0.0f;
            uint2 pk = { pack_bf16x2(ax * inv, ay * inv),
                         pack_bf16x2(az * inv, aw * inv) };
            *(uint2*)(sentb + (size_t)sidx * HID + t * 4) = pk;   // one 8B store
        }
    } else {
        // ---- weight transpose fp32[K][N] -> bf16[N][K], one 32x32 tile ----
        float* tile = (float*)smem;           // [32][33]
        const int id0 = blk - 512;
        const float* in; __hip_bfloat16* outw; int K, N, n0, k0;
        if (id0 < 3072) { in = W1; outw = W1T; K = 768;  N = 4096;
                          n0 = (id0 & 127) * 32; k0 = (id0 >> 7) * 32; }
        else { const int id = id0 - 3072;
               in = W2; outw = W2T; K = 4096; N = 256;
               n0 = (id & 7) * 32; k0 = (id >> 3) * 32; }
        const int c = t & 31;
        const int r = t >> 5;
        #pragma unroll
        for (int i = 0; i < 32; i += 8)
            tile[(r + i) * 33 + c] = in[(size_t)(k0 + r + i) * N + n0 + c];
        __syncthreads();
        #pragma unroll
        for (int i = 0; i < 32; i += 8)
            outw[(size_t)(n0 + r + i) * K + k0 + c] = __float2bfloat16(tile[c * 33 + r + i]);
    }
}

// ---------------------------------------------------------------------------
// K2: GEMM1  x1 = GELU(sentb[512,768] @ W1T[4096,768]^T + b1), bf16 out.
// 64x64 tile, BK=128 (6 K-iters), grid (64,8)=512 blocks (2/CU).
// 4 waves 2x2; each wave 32x32 via 2x2 MFMA x 4 k-steps = 16 MFMA/iter.
// Epilogue bounces through LDS for coalesced 32B stores.
// ---------------------------------------------------------------------------
__global__ __launch_bounds__(256) void gemm1_kernel(const __hip_bfloat16* __restrict__ A,
                                                    const __hip_bfloat16* __restrict__ BT,
                                                    const float* __restrict__ bias,
                                                    __hip_bfloat16* __restrict__ out) {
    const int n0 = blockIdx.x * 64;
    const int m0 = blockIdx.y * 64;
    const int t = threadIdx.x;
    const int w = t >> 6, l = t & 63;
    const int wm = (w >> 1) * 32;
    const int wn = (w & 1) * 32;

    __shared__ __hip_bfloat16 Al[64][136];
    __shared__ __hip_bfloat16 Bl[64][136];

    floatx4 acc[2][2] = {};

    const int r  = t >> 2;            // 0..63
    const int ch = (t & 3) * 32;      // 64B contiguous per thread
    const __hip_bfloat16* Ag = A  + (size_t)(m0 + r) * 768 + ch;
    const __hip_bfloat16* Bg = BT + (size_t)(n0 + r) * 768 + ch;

    const int lr = l & 15;
    const int kq = (l >> 4) * 8;

    for (int k0 = 0; k0 < 768; k0 += 128) {
        short8 av[4], bv[4];
        #pragma unroll
        for (int q = 0; q < 4; ++q) {
            av[q] = *(const short8*)(Ag + k0 + q * 8);
            bv[q] = *(const short8*)(Bg + k0 + q * 8);
        }
        __syncthreads();
        #pragma unroll
        for (int q = 0; q < 4; ++q) {
            *(short8*)(&Al[r][ch + q * 8]) = av[q];
            *(short8*)(&Bl[r][ch + q * 8]) = bv[q];
        }
        __syncthreads();

        #pragma unroll
        for (int ks = 0; ks < 128; ks += 32) {
            short8 a0 = *(const short8*)(&Al[wm + lr][ks + kq]);
            short8 a1 = *(const short8*)(&Al[wm + 16 + lr][ks + kq]);
            short8 b0 = *(const short8*)(&Bl[wn + lr][ks + kq]);
            short8 b1 = *(const short8*)(&Bl[wn + 16 + lr][ks + kq]);
            acc[0][0] = __builtin_amdgcn_mfma_f32_16x16x32_bf16(a0, b0, acc[0][0], 0, 0, 0);
            acc[0][1] = __builtin_amdgcn_mfma_f32_16x16x32_bf16(a0, b1, acc[0][1], 0, 0, 0);
            acc[1][0] = __builtin_amdgcn_mfma_f32_16x16x32_bf16(a1, b0, acc[1][0], 0, 0, 0);
            acc[1][1] = __builtin_amdgcn_mfma_f32_16x16x32_bf16(a1, b1, acc[1][1], 0, 0, 0);
        }
    }

    // ---- epilogue: bias + GELU -> LDS [64][72] -> coalesced 32B stores ----
    __syncthreads();
    __hip_bfloat16* E = &Al[0][0];              // reuse, stride 72
    #pragma unroll
    for (int i = 0; i < 2; ++i) {
        #pragma unroll
        for (int j = 0; j < 2; ++j) {
            const int cl = wn + j * 16 + lr;
            const float bv = bias[n0 + cl];
            #pragma unroll
            for (int rg = 0; rg < 4; ++rg) {
                const int rl = wm + i * 16 + (l >> 4) * 4 + rg;
                float x = acc[i][j][rg] + bv;
                E[rl * 72 + cl] = __float2bfloat16(gelu_exact(x));
            }
        }
    }
    __syncthreads();
    {
        const int rr  = t >> 2;
        const int seg = (t & 3) * 16;
        short8 v0 = *(const short8*)(&E[rr * 72 + seg]);
        short8 v1 = *(const short8*)(&E[rr * 72 + seg + 8]);
        __hip_bfloat16* op = out + (size_t)(m0 + rr) * 4096 + n0 + seg;
        *(short8*)(op)     = v0;
        *(short8*)(op + 8) = v1;
    }
}

// ---------------------------------------------------------------------------
// K3: GEMM2 partials: part[s] = x1[512, 512-slice] @ W2T[256, 512-slice]^T.
// Split-K=8 (512 K each), BK=128 -> 4 K-iters. Grid (4,8,8)=256 blocks.
// ---------------------------------------------------------------------------
__global__ __launch_bounds__(256) void gemm2_kernel(const __hip_bfloat16* __restrict__ A,
                                                    const __hip_bfloat16* __restrict__ BT,
                                                    float* __restrict__ part) {
    const int n0 = blockIdx.x * 64;
    const int m0 = blockIdx.y * 64;
    const int s  = blockIdx.z;
    const int kb = s * 512;
    const int t = threadIdx.x;
    const int w = t >> 6, l = t & 63;
    const int wm = (w >> 1) * 32;
    const int wn = (w & 1) * 32;

    __shared__ __hip_bfloat16 Al[64][136];
    __shared__ __hip_bfloat16 Bl[64][136];

    floatx4 acc[2][2] = {};

    const int r  = t >> 2;
    const int ch = (t & 3) * 32;
    const __hip_bfloat16* Ag = A  + (size_t)(m0 + r) * 4096 + kb + ch;
    const __hip_bfloat16* Bg = BT + (size_t)(n0 + r) * 4096 + kb + ch;

    const int lr = l & 15;
    const int kq = (l >> 4) * 8;

    for (int k0 = 0; k0 < 512; k0 += 128) {
        short8 av[4], bv[4];
        #pragma unroll
        for (int q = 0; q < 4; ++q) {
            av[q] = *(const short8*)(Ag + k0 + q * 8);
            bv[q] = *(const short8*)(Bg + k0 + q * 8);
        }
        __syncthreads();
        #pragma unroll
        for (int q = 0; q < 4; ++q) {
            *(short8*)(&Al[r][ch + q * 8]) = av[q];
            *(short8*)(&Bl[r][ch + q * 8]) = bv[q];
        }
        __syncthreads();

        #pragma unroll
        for (int ks = 0; ks < 128; ks += 32) {
            short8 a0 = *(const short8*)(&Al[wm + lr][ks + kq]);
            short8 a1 = *(const short8*)(&Al[wm + 16 + lr][ks + kq]);
            short8 b0 = *(const short8*)(&Bl[wn + lr][ks + kq]);
            short8 b1 = *(const short8*)(&Bl[wn + 16 + lr][ks + kq]);
            acc[0][0] = __builtin_amdgcn_mfma_f32_16x16x32_bf16(a0, b0, acc[0][0], 0, 0, 0);
            acc[0][1] = __builtin_amdgcn_mfma_f32_16x16x32_bf16(a0, b1, acc[0][1], 0, 0, 0);
            acc[1][0] = __builtin_amdgcn_mfma_f32_16x16x32_bf16(a1, b0, acc[1][0], 0, 0, 0);
            acc[1][1] = __builtin_amdgcn_mfma_f32_16x16x32_bf16(a1, b1, acc[1][1], 0, 0, 0);
        }
    }

    float* po = part + (size_t)s * 512 * 256;
    #pragma unroll
    for (int i = 0; i < 2; ++i) {
        #pragma unroll
        for (int j = 0; j < 2; ++j) {
            const int col  = n0 + wn + j * 16 + lr;
            const int rowb = m0 + wm + i * 16 + (l >> 4) * 4;
            #pragma unroll
            for (int rg = 0; rg < 4; ++rg)
                po[(size_t)(rowb + rg) * 256 + col] = acc[i][j][rg];
        }
    }
}

// ---------------------------------------------------------------------------
// K4: fused reduce(8 split-K partials) + b2 + GELU + head (W3[256,2]+b3).
// ---------------------------------------------------------------------------
__global__ __launch_bounds__(256) void rh_kernel(const float* __restrict__ part,
                                                 const float* __restrict__ b2,
                                                 const float* __restrict__ W3,
                                                 const float* __restrict__ b3,
                                                 float* __restrict__ out) {
    const int row = blockIdx.x;     // 512
    const int c = threadIdx.x;      // 256
    const int w = c >> 6, l = c & 63;

    float s = 0.f;
    #pragma unroll
    for (int k = 0; k < 8; ++k)
        s += part[((size_t)k * 512 + row) * 256 + c];
    const float x = gelu_exact(s + b2[c]);
    float y0 = x * W3[c * 2 + 0];
    float y1 = x * W3[c * 2 + 1];
    #pragma unroll
    for (int off = 32; off; off >>= 1) {
        y0 += __shfl_down(y0, off);
        y1 += __shfl_down(y1, off);
    }
    __shared__ float r0[4], r1[4];
    if (l == 0) { r0[w] = y0; r1[w] = y1; }
    __syncthreads();
    if (c == 0) out[row * 2 + 0] = r0[0] + r0[1] + r0[2] + r0[3] + b3[0];
    if (c == 1) out[row * 2 + 1] = r1[0] + r1[1] + r1[2] + r1[3] + b3[1];
}

// ---------------------------------------------------------------------------
extern "C" void kernel_launch(void* const* d_in, const int* in_sizes, int n_in,
                              void* d_out, int out_size, void* d_ws, size_t ws_size,
                              hipStream_t stream) {
    const float* hidden = (const float*)d_in[0];
    const int*   ids    = (const int*)d_in[1];
    const float* W1     = (const float*)d_in[2];
    const float* b1     = (const float*)d_in[3];
    const float* W2     = (const float*)d_in[4];
    const float* b2     = (const float*)d_in[5];
    const float* W3     = (const float*)d_in[6];
    const float* b3     = (const float*)d_in[7];
    float* out = (float*)d_out;

    char* ws = (char*)d_ws;
    __hip_bfloat16* sentb  = (__hip_bfloat16*)(ws + 0);           // 512x768 bf16
    __hip_bfloat16* W1T    = (__hip_bfloat16*)(ws + 786432);      // 4096x768 bf16
    __hip_bfloat16* W2T    = (__hip_bfloat16*)(ws + 7077888);     // 256x4096 bf16
    __hip_bfloat16* x1     = (__hip_bfloat16*)(ws + 9175040);     // 512x4096 bf16
    float* part            = (float*)(ws + 13369344);             // 8x512x256 f32
    // total ws use: ~17.6 MB

    stage1_kernel<<<4608, 256, 0, stream>>>(ids, hidden, W1, W2, W1T, W2T, sentb);
    gemm1_kernel<<<dim3(64, 8), 256, 0, stream>>>(sentb, W1T, b1, x1);
    gemm2_kernel<<<dim3(4, 8, 8), 256, 0, stream>>>(x1, W2T, part);
    rh_kernel<<<512, 256, 0, stream>>>(part, b2, W3, b3, out);
}

// Round 11
// 194.651 us; speedup vs baseline: 1.2864x; 1.0138x over previous
//
#include <hip/hip_runtime.h>
#include <hip/hip_bf16.h>

#define SEP_ID 2
#define S_LEN  4096
#define HID    768
#define MAXS   64

using short8  = __attribute__((ext_vector_type(8))) short;  // 8 bf16 (4 VGPRs)
using floatx4 = __attribute__((ext_vector_type(4))) float;  // MFMA accumulator

__device__ __forceinline__ float gelu_exact(float x) {
    return 0.5f * x * (1.0f + erff(x * 0.70710678118654752f));
}

__device__ __forceinline__ unsigned pack_bf16x2(float lo, float hi) {
    __hip_bfloat16 a = __float2bfloat16(lo);
    __hip_bfloat16 b = __float2bfloat16(hi);
    return ((unsigned)*(unsigned short*)&b << 16) | (unsigned)*(unsigned short*)&a;
}

// ---------------------------------------------------------------------------
// K1 "stage1": pool blocks [0,512) + weight-transpose blocks [512,4608).
// R10 diagnosis: dynamically-indexed local[16] forced scratch; compiler then
// spilled the float4 v[8] batch -> pool loop serialized through scratch
// (VGPR_Count=32, 62us, 1.1TB/s). This version is scratch-free: the sep scan
// is two passes over int4s held in registers (static indexing only), writing
// positions directly to LDS.
// ---------------------------------------------------------------------------
__global__ __launch_bounds__(256, 2) void stage1_kernel(const int* __restrict__ ids,
                                                        const float* __restrict__ hidden,
                                                        const float* __restrict__ W1,
                                                        const float* __restrict__ W2,
                                                        __hip_bfloat16* __restrict__ W1T,
                                                        __hip_bfloat16* __restrict__ W2T,
                                                        __hip_bfloat16* __restrict__ sentb) {
    __shared__ __align__(16) char smem[16640];
    const int blk = blockIdx.x;
    const int t = threadIdx.x;

    if (blk < 512) {
        // ---- self-bounds (scratch-free) ----
        int* sep_pos = (int*)smem;            // 4096 ints
        int* wtot    = sep_pos + 4096;        // 4 ints
        const int sidx = blk;
        const int b = sidx >> 6, m = sidx & 63;
        const int* row = ids + (size_t)b * S_LEN;
        const int lane = t & 63, w = t >> 6;
        const int base = t * 16;

        int4 vq[4];                                // 16 tokens in registers
        #pragma unroll
        for (int q = 0; q < 4; ++q) vq[q] = ((const int4*)row)[t * 4 + q];

        int c = 0;                                 // pass 1: count
        #pragma unroll
        for (int q = 0; q < 4; ++q) {
            c += (vq[q].x == SEP_ID) + (vq[q].y == SEP_ID)
               + (vq[q].z == SEP_ID) + (vq[q].w == SEP_ID);
        }
        int scan = c;                              // inclusive wave prefix
        #pragma unroll
        for (int off = 1; off < 64; off <<= 1) {
            int n = __shfl_up(scan, off);
            if (lane >= off) scan += n;
        }
        if (lane == 63) wtot[w] = scan;
        __syncthreads();
        int wbase = 0;
        for (int i = 0; i < w; ++i) wbase += wtot[i];
        int oo = wbase + scan - c;                 // exclusive offset
        #pragma unroll
        for (int q = 0; q < 4; ++q) {              // pass 2: write to LDS
            if (vq[q].x == SEP_ID) sep_pos[oo++] = base + q * 4 + 0;
            if (vq[q].y == SEP_ID) sep_pos[oo++] = base + q * 4 + 1;
            if (vq[q].z == SEP_ID) sep_pos[oo++] = base + q * 4 + 2;
            if (vq[q].w == SEP_ID) sep_pos[oo++] = base + q * 4 + 3;
        }
        __syncthreads();
        const int n_sep = wtot[0] + wtot[1] + wtot[2] + wtot[3];

        // ---- reference segment semantics ----
        int start = 0, cntok = 0;
        if (n_sep == 0) {
            if (m == 0) { start = 0; cntok = S_LEN; }
        } else if (m < n_sep) {
            if (m == 0) { start = 0; cntok = sep_pos[0] + 1; }   // includes first sep
            else { start = sep_pos[m - 1] + 1; cntok = sep_pos[m] - sep_pos[m - 1] - 1; }
        } else if (m == n_sep) {
            start = sep_pos[n_sep - 1] + 1;                      // trailing segment
            cntok = (S_LEN - 1) - start;                         // excludes token S-1
            if (cntok < 0) cntok = 0;
        }

        // ---- mean pool: 192 threads own one float4 column each ----
        if (t < 192) {
            const float4* bp = (const float4*)(hidden + ((size_t)b * S_LEN + start) * HID);
            float ax = 0.f, ay = 0.f, az = 0.f, aw = 0.f;
            int i = 0;
            for (; i + 8 <= cntok; i += 8) {       // 8 x 16B in flight
                float4 v[8];
                #pragma unroll
                for (int j = 0; j < 8; ++j) v[j] = bp[(size_t)(i + j) * 192 + t];
                #pragma unroll
                for (int j = 0; j < 8; ++j) { ax += v[j].x; ay += v[j].y; az += v[j].z; aw += v[j].w; }
            }
            for (; i + 4 <= cntok; i += 4) {       // unroll-4 mid-tail
                float4 v[4];
                #pragma unroll
                for (int j = 0; j < 4; ++j) v[j] = bp[(size_t)(i + j) * 192 + t];
                #pragma unroll
                for (int j = 0; j < 4; ++j) { ax += v[j].x; ay += v[j].y; az += v[j].z; aw += v[j].w; }
            }
            for (; i < cntok; ++i) {
                float4 v = bp[(size_t)i * 192 + t];
                ax += v.x; ay += v.y; az += v.z; aw += v.w;
            }
            const float inv = (cntok > 0) ? 1.0f / (float)cntok : 0.0f;
            uint2 pk = { pack_bf16x2(ax * inv, ay * inv),
                         pack_bf16x2(az * inv, aw * inv) };
            *(uint2*)(sentb + (size_t)sidx * HID + t * 4) = pk;   // one 8B store
        }
    } else {
        // ---- weight transpose fp32[K][N] -> bf16[N][K], one 32x32 tile ----
        float* tile = (float*)smem;           // [32][33]
        const int id0 = blk - 512;
        const float* in; __hip_bfloat16* outw; int K, N, n0, k0;
        if (id0 < 3072) { in = W1; outw = W1T; K = 768;  N = 4096;
                          n0 = (id0 & 127) * 32; k0 = (id0 >> 7) * 32; }
        else { const int id = id0 - 3072;
               in = W2; outw = W2T; K = 4096; N = 256;
               n0 = (id & 7) * 32; k0 = (id >> 3) * 32; }
        const int c = t & 31;
        const int r = t >> 5;
        #pragma unroll
        for (int i = 0; i < 32; i += 8)
            tile[(r + i) * 33 + c] = in[(size_t)(k0 + r + i) * N + n0 + c];
        __syncthreads();
        #pragma unroll
        for (int i = 0; i < 32; i += 8)
            outw[(size_t)(n0 + r + i) * K + k0 + c] = __float2bfloat16(tile[c * 33 + r + i]);
    }
}

// ---------------------------------------------------------------------------
// K2: GEMM1  x1 = GELU(sentb[512,768] @ W1T[4096,768]^T + b1), bf16 out.
// 64x64 tile, BK=128 (6 K-iters), grid (64,8)=512 blocks (2/CU).
// 4 waves 2x2; each wave 32x32 via 2x2 MFMA x 4 k-steps = 16 MFMA/iter.
// Epilogue bounces through LDS for coalesced 32B stores.
// ---------------------------------------------------------------------------
__global__ __launch_bounds__(256) void gemm1_kernel(const __hip_bfloat16* __restrict__ A,
                                                    const __hip_bfloat16* __restrict__ BT,
                                                    const float* __restrict__ bias,
                                                    __hip_bfloat16* __restrict__ out) {
    const int n0 = blockIdx.x * 64;
    const int m0 = blockIdx.y * 64;
    const int t = threadIdx.x;
    const int w = t >> 6, l = t & 63;
    const int wm = (w >> 1) * 32;
    const int wn = (w & 1) * 32;

    __shared__ __hip_bfloat16 Al[64][136];
    __shared__ __hip_bfloat16 Bl[64][136];

    floatx4 acc[2][2] = {};

    const int r  = t >> 2;            // 0..63
    const int ch = (t & 3) * 32;      // 64B contiguous per thread
    const __hip_bfloat16* Ag = A  + (size_t)(m0 + r) * 768 + ch;
    const __hip_bfloat16* Bg = BT + (size_t)(n0 + r) * 768 + ch;

    const int lr = l & 15;
    const int kq = (l >> 4) * 8;

    for (int k0 = 0; k0 < 768; k0 += 128) {
        short8 av[4], bv[4];
        #pragma unroll
        for (int q = 0; q < 4; ++q) {
            av[q] = *(const short8*)(Ag + k0 + q * 8);
            bv[q] = *(const short8*)(Bg + k0 + q * 8);
        }
        __syncthreads();
        #pragma unroll
        for (int q = 0; q < 4; ++q) {
            *(short8*)(&Al[r][ch + q * 8]) = av[q];
            *(short8*)(&Bl[r][ch + q * 8]) = bv[q];
        }
        __syncthreads();

        #pragma unroll
        for (int ks = 0; ks < 128; ks += 32) {
            short8 a0 = *(const short8*)(&Al[wm + lr][ks + kq]);
            short8 a1 = *(const short8*)(&Al[wm + 16 + lr][ks + kq]);
            short8 b0 = *(const short8*)(&Bl[wn + lr][ks + kq]);
            short8 b1 = *(const short8*)(&Bl[wn + 16 + lr][ks + kq]);
            acc[0][0] = __builtin_amdgcn_mfma_f32_16x16x32_bf16(a0, b0, acc[0][0], 0, 0, 0);
            acc[0][1] = __builtin_amdgcn_mfma_f32_16x16x32_bf16(a0, b1, acc[0][1], 0, 0, 0);
            acc[1][0] = __builtin_amdgcn_mfma_f32_16x16x32_bf16(a1, b0, acc[1][0], 0, 0, 0);
            acc[1][1] = __builtin_amdgcn_mfma_f32_16x16x32_bf16(a1, b1, acc[1][1], 0, 0, 0);
        }
    }

    // ---- epilogue: bias + GELU -> LDS [64][72] -> coalesced 32B stores ----
    __syncthreads();
    __hip_bfloat16* E = &Al[0][0];              // reuse, stride 72
    #pragma unroll
    for (int i = 0; i < 2; ++i) {
        #pragma unroll
        for (int j = 0; j < 2; ++j) {
            const int cl = wn + j * 16 + lr;
            const float bv = bias[n0 + cl];
            #pragma unroll
            for (int rg = 0; rg < 4; ++rg) {
                const int rl = wm + i * 16 + (l >> 4) * 4 + rg;
                float x = acc[i][j][rg] + bv;
                E[rl * 72 + cl] = __float2bfloat16(gelu_exact(x));
            }
        }
    }
    __syncthreads();
    {
        const int rr  = t >> 2;
        const int seg = (t & 3) * 16;
        short8 v0 = *(const short8*)(&E[rr * 72 + seg]);
        short8 v1 = *(const short8*)(&E[rr * 72 + seg + 8]);
        __hip_bfloat16* op = out + (size_t)(m0 + rr) * 4096 + n0 + seg;
        *(short8*)(op)     = v0;
        *(short8*)(op + 8) = v1;
    }
}

// ---------------------------------------------------------------------------
// K3: GEMM2 partials: part[s] = x1[512, 512-slice] @ W2T[256, 512-slice]^T.
// Split-K=8 (512 K each), BK=128 -> 4 K-iters. Grid (4,8,8)=256 blocks.
// ---------------------------------------------------------------------------
__global__ __launch_bounds__(256) void gemm2_kernel(const __hip_bfloat16* __restrict__ A,
                                                    const __hip_bfloat16* __restrict__ BT,
                                                    float* __restrict__ part) {
    const int n0 = blockIdx.x * 64;
    const int m0 = blockIdx.y * 64;
    const int s  = blockIdx.z;
    const int kb = s * 512;
    const int t = threadIdx.x;
    const int w = t >> 6, l = t & 63;
    const int wm = (w >> 1) * 32;
    const int wn = (w & 1) * 32;

    __shared__ __hip_bfloat16 Al[64][136];
    __shared__ __hip_bfloat16 Bl[64][136];

    floatx4 acc[2][2] = {};

    const int r  = t >> 2;
    const int ch = (t & 3) * 32;
    const __hip_bfloat16* Ag = A  + (size_t)(m0 + r) * 4096 + kb + ch;
    const __hip_bfloat16* Bg = BT + (size_t)(n0 + r) * 4096 + kb + ch;

    const int lr = l & 15;
    const int kq = (l >> 4) * 8;

    for (int k0 = 0; k0 < 512; k0 += 128) {
        short8 av[4], bv[4];
        #pragma unroll
        for (int q = 0; q < 4; ++q) {
            av[q] = *(const short8*)(Ag + k0 + q * 8);
            bv[q] = *(const short8*)(Bg + k0 + q * 8);
        }
        __syncthreads();
        #pragma unroll
        for (int q = 0; q < 4; ++q) {
            *(short8*)(&Al[r][ch + q * 8]) = av[q];
            *(short8*)(&Bl[r][ch + q * 8]) = bv[q];
        }
        __syncthreads();

        #pragma unroll
        for (int ks = 0; ks < 128; ks += 32) {
            short8 a0 = *(const short8*)(&Al[wm + lr][ks + kq]);
            short8 a1 = *(const short8*)(&Al[wm + 16 + lr][ks + kq]);
            short8 b0 = *(const short8*)(&Bl[wn + lr][ks + kq]);
            short8 b1 = *(const short8*)(&Bl[wn + 16 + lr][ks + kq]);
            acc[0][0] = __builtin_amdgcn_mfma_f32_16x16x32_bf16(a0, b0, acc[0][0], 0, 0, 0);
            acc[0][1] = __builtin_amdgcn_mfma_f32_16x16x32_bf16(a0, b1, acc[0][1], 0, 0, 0);
            acc[1][0] = __builtin_amdgcn_mfma_f32_16x16x32_bf16(a1, b0, acc[1][0], 0, 0, 0);
            acc[1][1] = __builtin_amdgcn_mfma_f32_16x16x32_bf16(a1, b1, acc[1][1], 0, 0, 0);
        }
    }

    float* po = part + (size_t)s * 512 * 256;
    #pragma unroll
    for (int i = 0; i < 2; ++i) {
        #pragma unroll
        for (int j = 0; j < 2; ++j) {
            const int col  = n0 + wn + j * 16 + lr;
            const int rowb = m0 + wm + i * 16 + (l >> 4) * 4;
            #pragma unroll
            for (int rg = 0; rg < 4; ++rg)
                po[(size_t)(rowb + rg) * 256 + col] = acc[i][j][rg];
        }
    }
}

// ---------------------------------------------------------------------------
// K4: fused reduce(8 split-K partials) + b2 + GELU + head (W3[256,2]+b3).
// ---------------------------------------------------------------------------
__global__ __launch_bounds__(256) void rh_kernel(const float* __restrict__ part,
                                                 const float* __restrict__ b2,
                                                 const float* __restrict__ W3,
                                                 const float* __restrict__ b3,
                                                 float* __restrict__ out) {
    const int row = blockIdx.x;     // 512
    const int c = threadIdx.x;      // 256
    const int w = c >> 6, l = c & 63;

    float s = 0.f;
    #pragma unroll
    for (int k = 0; k < 8; ++k)
        s += part[((size_t)k * 512 + row) * 256 + c];
    const float x = gelu_exact(s + b2[c]);
    float y0 = x * W3[c * 2 + 0];
    float y1 = x * W3[c * 2 + 1];
    #pragma unroll
    for (int off = 32; off; off >>= 1) {
        y0 += __shfl_down(y0, off);
        y1 += __shfl_down(y1, off);
    }
    __shared__ float r0[4], r1[4];
    if (l == 0) { r0[w] = y0; r1[w] = y1; }
    __syncthreads();
    if (c == 0) out[row * 2 + 0] = r0[0] + r0[1] + r0[2] + r0[3] + b3[0];
    if (c == 1) out[row * 2 + 1] = r1[0] + r1[1] + r1[2] + r1[3] + b3[1];
}

// ---------------------------------------------------------------------------
extern "C" void kernel_launch(void* const* d_in, const int* in_sizes, int n_in,
                              void* d_out, int out_size, void* d_ws, size_t ws_size,
                              hipStream_t stream) {
    const float* hidden = (const float*)d_in[0];
    const int*   ids    = (const int*)d_in[1];
    const float* W1     = (const float*)d_in[2];
    const float* b1     = (const float*)d_in[3];
    const float* W2     = (const float*)d_in[4];
    const float* b2     = (const float*)d_in[5];
    const float* W3     = (const float*)d_in[6];
    const float* b3     = (const float*)d_in[7];
    float* out = (float*)d_out;

    char* ws = (char*)d_ws;
    __hip_bfloat16* sentb  = (__hip_bfloat16*)(ws + 0);           // 512x768 bf16
    __hip_bfloat16* W1T    = (__hip_bfloat16*)(ws + 786432);      // 4096x768 bf16
    __hip_bfloat16* W2T    = (__hip_bfloat16*)(ws + 7077888);     // 256x4096 bf16
    __hip_bfloat16* x1     = (__hip_bfloat16*)(ws + 9175040);     // 512x4096 bf16
    float* part            = (float*)(ws + 13369344);             // 8x512x256 f32
    // total ws use: ~17.6 MB

    stage1_kernel<<<4608, 256, 0, stream>>>(ids, hidden, W1, W2, W1T, W2T, sentb);
    gemm1_kernel<<<dim3(64, 8), 256, 0, stream>>>(sentb, W1T, b1, x1);
    gemm2_kernel<<<dim3(4, 8, 8), 256, 0, stream>>>(x1, W2T, part);
    rh_kernel<<<512, 256, 0, stream>>>(part, b2, W3, b3, out);
}